// Round 2
// baseline (715.645 us; speedup 1.0000x reference)
//
#include <hip/hip_runtime.h>
#include <stdint.h>
#include <stddef.h>

// EfficientAttention: B=4, L=4096, D=1024, H=16, hd=64.
// detect_dtype -> flag in d_ws; then dual pipelines (bf16 / fp32-split), each
// early-exits unless flag matches. Phase 1: Q,K,V = X @ W^T (MFMA). Phase 2:
// per-token head-mixing softmax matmuls.
#define TOKENS 16384
#define DMODEL 1024

typedef short   short8 __attribute__((ext_vector_type(8)));
typedef __bf16  bfx8   __attribute__((ext_vector_type(8)));
typedef float   f32x4  __attribute__((ext_vector_type(4)));
typedef unsigned short ushort_t;

__device__ inline float bf2f(ushort_t u) {
  union { unsigned int i; float f; } x; x.i = ((unsigned int)u) << 16; return x.f;
}
__device__ inline ushort_t f2bf(float f) {
  union { float f; unsigned int i; } x; x.f = f;
  unsigned int r = x.i + 0x7fff + ((x.i >> 16) & 1);
  return (ushort_t)(r >> 16);
}

// ---- MFMA wrapper: dual-signature hedge (short8 vs v8bf16 builtin arg) ----
template <typename V>
__device__ auto mfma16_(V a, V b, f32x4 c, int)
    -> decltype(__builtin_amdgcn_mfma_f32_16x16x32_bf16(a, b, c, 0, 0, 0)) {
  return __builtin_amdgcn_mfma_f32_16x16x32_bf16(a, b, c, 0, 0, 0);
}
template <typename V>
__device__ f32x4 mfma16_(V a, V b, f32x4 c, long) {
  return __builtin_amdgcn_mfma_f32_16x16x32_bf16(
      __builtin_bit_cast(bfx8, a), __builtin_bit_cast(bfx8, b), c, 0, 0, 0);
}
__device__ inline f32x4 MFMA16(short8 a, short8 b, f32x4 c) {
  return mfma16_(a, b, c, 0);
}

__device__ inline void gload_lds16(const void* g, void* l) {
  __builtin_amdgcn_global_load_lds(
      (const __attribute__((address_space(1))) unsigned int*)g,
      (__attribute__((address_space(3))) unsigned int*)l, 16, 0, 0);
}

// split fp32 -> bf16 hi + bf16 lo (x ~= hi + lo, residual ~2^-17 |x|)
__device__ inline void split8(const float* p, short8& hi, short8& lo) {
  const f32x4* v = (const f32x4*)p;
  f32x4 x0 = v[0], x1 = v[1];
  #pragma unroll
  for (int j = 0; j < 4; ++j) {
    float x = x0[j]; ushort_t h = f2bf(x); float r = x - bf2f(h);
    hi[j] = (short)h; lo[j] = (short)f2bf(r);
  }
  #pragma unroll
  for (int j = 0; j < 4; ++j) {
    float x = x1[j]; ushort_t h = f2bf(x); float r = x - bf2f(h);
    hi[4 + j] = (short)h; lo[4 + j] = (short)f2bf(r);
  }
}

// ---- dtype detector: low 16 bits of fp32 words are uniform mantissa bits
// (exp field >= 0x88 ~47% of the time); low halves of packed bf16 N(0,1)
// data never have exp >= 0x88 (|x| >= 512). Deterministic per input.
__global__ void detect_dtype(const unsigned int* __restrict__ x, int* __restrict__ flag) {
  int lane = threadIdx.x & 63;
  int cnt = 0;
  for (int i = 0; i < 64; ++i) {
    unsigned w = x[lane * 64 + i];
    unsigned ex = ((w & 0xffffu) >> 7) & 0xff;
    cnt += (ex >= 0x88) ? 1 : 0;
  }
  for (int off = 32; off; off >>= 1) cnt += __shfl_xor(cnt, off);
  if (lane == 0) *flag = (cnt > 200) ? 1 : 0;
}

// ---------------- Phase 1: Y[z] = X @ W[z]^T ----------------
// 128x128 tile, BK=32, 256 threads (4 waves, 2x2 grid, 64x64/wave).
// TIN=ushort_t: single MFMA; TIN=float: hi/lo split, 3 MFMAs.
template <typename TIN, typename TY, int WANT>
__global__ __launch_bounds__(256, 2) void qkv_gemm(
    const int* __restrict__ flag,
    const TIN* __restrict__ X, const TIN* __restrict__ Wq,
    const TIN* __restrict__ Wk, const TIN* __restrict__ Wv,
    TY* __restrict__ Y)
{
  if (*flag != WANT) return;

  __shared__ TIN As[128 * 32];
  __shared__ TIN Bs[128 * 32];

  constexpr int EPC = 16 / (int)sizeof(TIN);   // elems per 16B chunk (8 or 4)
  constexpr int CPR = 32 / EPC;                // chunks per row (4 or 8)
  constexpr int PASSES = 128 * CPR / 256;      // staging passes (2 or 4)
  constexpr int RPP = 256 / CPR;               // rows per pass (64 or 32)

  const int tid  = threadIdx.x;
  const int lane = tid & 63;
  const int wave = tid >> 6;
  const int quad = lane >> 4;
  const int l15  = lane & 15;
  const int wm   = wave & 1, wn = wave >> 1;

  const int m0 = blockIdx.x * 128;
  const int n0 = blockIdx.y * 128;
  const TIN* W = (blockIdx.z == 0) ? Wq : ((blockIdx.z == 1) ? Wk : Wv);
  TY* Yp = Y + (size_t)blockIdx.z * TOKENS * DMODEL;

  const TIN* Ag = X + (size_t)m0 * DMODEL;
  const TIN* Bg = W + (size_t)n0 * DMODEL;

  const int s_row = tid / CPR;
  const int s_off = (tid % CPR) * EPC;

  f32x4 acc[4][4] = {};

  for (int k0 = 0; k0 < DMODEL; k0 += 32) {
    #pragma unroll
    for (int p = 0; p < PASSES; ++p) {
      size_t goff = (size_t)(p * RPP + s_row) * DMODEL + k0 + s_off;
      gload_lds16(Ag + goff, (char*)As + (p * 256 + wave * 64) * 16);
      gload_lds16(Bg + goff, (char*)Bs + (p * 256 + wave * 64) * 16);
    }
    __syncthreads();  // compiler drains vmcnt(0) before barrier

    short8 ahi[4], bhi[4], alo[4], blo[4];
    if constexpr (sizeof(TIN) == 2) {
      const short8* Asv = (const short8*)As;
      const short8* Bsv = (const short8*)Bs;
      #pragma unroll
      for (int i = 0; i < 4; ++i) ahi[i] = Asv[(wm * 64 + i * 16 + l15) * 4 + quad];
      #pragma unroll
      for (int j = 0; j < 4; ++j) bhi[j] = Bsv[(wn * 64 + j * 16 + l15) * 4 + quad];
    } else {
      #pragma unroll
      for (int i = 0; i < 4; ++i)
        split8((const float*)As + (wm * 64 + i * 16 + l15) * 32 + quad * 8, ahi[i], alo[i]);
      #pragma unroll
      for (int j = 0; j < 4; ++j)
        split8((const float*)Bs + (wn * 64 + j * 16 + l15) * 32 + quad * 8, bhi[j], blo[j]);
    }

    #pragma unroll
    for (int i = 0; i < 4; ++i) {
      #pragma unroll
      for (int j = 0; j < 4; ++j) {
        acc[i][j] = MFMA16(ahi[i], bhi[j], acc[i][j]);
        if constexpr (sizeof(TIN) == 4) {
          acc[i][j] = MFMA16(alo[i], bhi[j], acc[i][j]);
          acc[i][j] = MFMA16(ahi[i], blo[j], acc[i][j]);
        }
      }
    }
    __syncthreads();
  }

  // C/D layout: col = lane&15, row = quad*4 + reg
  #pragma unroll
  for (int i = 0; i < 4; ++i) {
    #pragma unroll
    for (int j = 0; j < 4; ++j) {
      #pragma unroll
      for (int r = 0; r < 4; ++r) {
        int row = m0 + wm * 64 + i * 16 + quad * 4 + r;
        int col = n0 + wn * 64 + j * 16 + l15;
        float v = acc[i][j][r];
        if constexpr (sizeof(TY) == 2) Yp[(size_t)row * DMODEL + col] = f2bf(v);
        else                           Yp[(size_t)row * DMODEL + col] = v;
      }
    }
  }
}

// ---------------- Phase 2: per-token mixing ----------------
__device__ inline float ldf(const ushort_t* p) { return bf2f(*p); }
__device__ inline float ldf(const float* p)    { return *p; }

template <typename TY, typename TOUT, int WANT>
__global__ __launch_bounds__(256) void attn_mix(
    const int* __restrict__ flag,
    const TY* __restrict__ QKV, TOUT* __restrict__ Out)
{
  if (*flag != WANT) return;

  __shared__ float sk_s[4][64 * 20];
  __shared__ float smq_s[4][16 * 64];

  const int tid  = threadIdx.x;
  const int lane = tid & 63;
  const int wv   = tid >> 6;
  const int tok  = blockIdx.x * 4 + wv;

  float* skl = sk_s[wv];
  float* smq = smq_s[wv];

  const size_t base = (size_t)tok * DMODEL;
  const TY* Qg = QKV + base;
  const TY* Kg = QKV + (size_t)TOKENS * DMODEL + base;
  const TY* Vg = QKV + 2 * (size_t)TOKENS * DMODEL + base;

  float q[16], k[16], v[16];
  #pragma unroll
  for (int h = 0; h < 16; ++h) {
    q[h] = ldf(Qg + h * 64 + lane);
    k[h] = ldf(Kg + h * 64 + lane);
    v[h] = ldf(Vg + h * 64 + lane);
  }

  // sK[d][h] = softmax over h of K[h][d]; d = lane (per-lane)
  float mx = k[0];
  #pragma unroll
  for (int h = 1; h < 16; ++h) mx = fmaxf(mx, k[h]);
  float ssum = 0.f;
  #pragma unroll
  for (int h = 0; h < 16; ++h) { k[h] = __expf(k[h] - mx); ssum += k[h]; }
  float inv = 1.f / ssum;
  #pragma unroll
  for (int h = 0; h < 16; ++h) skl[lane * 20 + h] = k[h] * inv;

  // smQ[h][d] = softmax over d of Q[h][d]; wave reductions
  #pragma unroll
  for (int h = 0; h < 16; ++h) {
    float m = q[h];
    for (int off = 32; off; off >>= 1) m = fmaxf(m, __shfl_xor(m, off));
    float e = __expf(q[h] - m);
    float s2 = e;
    for (int off = 32; off; off >>= 1) s2 += __shfl_xor(s2, off);
    smq[h * 64 + lane] = e / s2;
  }

  __syncthreads();

  // tran_V col e(=lane): tv[d] = sum_h sK[d][h] * V[h][e]
  float tv[64];
  #pragma unroll
  for (int d = 0; d < 64; ++d) {
    const f32x4* r = (const f32x4*)(skl + d * 20);
    f32x4 s0 = r[0], s1 = r[1], s2 = r[2], s3 = r[3];
    float t = 0.f;
    #pragma unroll
    for (int h = 0; h < 4; ++h)
      t += s0[h] * v[h] + s1[h] * v[4 + h] + s2[h] * v[8 + h] + s3[h] * v[12 + h];
    tv[d] = t;
  }

  // out[h][e] = sum_d smQ[h][d] * tv[d]
  #pragma unroll
  for (int h = 0; h < 16; ++h) {
    const f32x4* r = (const f32x4*)(smq + h * 64);
    float o = 0.f;
    #pragma unroll
    for (int d4 = 0; d4 < 16; ++d4) {
      f32x4 w = r[d4];
      o += w[0] * tv[d4 * 4] + w[1] * tv[d4 * 4 + 1] + w[2] * tv[d4 * 4 + 2] + w[3] * tv[d4 * 4 + 3];
    }
    float val = o;
    if constexpr (sizeof(TOUT) == 2) Out[base + h * 64 + lane] = f2bf(val);
    else                             Out[base + h * 64 + lane] = val;
  }
}

extern "C" void kernel_launch(void* const* d_in, const int* in_sizes, int n_in,
                              void* d_out, int out_size, void* d_ws, size_t ws_size,
                              hipStream_t stream) {
  int*  flag = (int*)d_ws;
  char* ybuf = (char*)d_ws + 256;
  const size_t y_f32_bytes = 3ull * TOKENS * DMODEL * 4;
  const bool y32 = ws_size >= 256 + y_f32_bytes;

  detect_dtype<<<1, 64, 0, stream>>>((const unsigned int*)d_in[0], flag);

  dim3 g1(TOKENS / 128, DMODEL / 128, 3);

  // bf16 pipeline (flag == 0)
  qkv_gemm<ushort_t, ushort_t, 0><<<g1, 256, 0, stream>>>(
      flag, (const ushort_t*)d_in[0], (const ushort_t*)d_in[1],
      (const ushort_t*)d_in[2], (const ushort_t*)d_in[3], (ushort_t*)ybuf);
  attn_mix<ushort_t, ushort_t, 0><<<TOKENS / 4, 256, 0, stream>>>(
      flag, (const ushort_t*)ybuf, (ushort_t*)d_out);

  // fp32 pipeline (flag == 1), split-bf16 GEMM
  if (y32) {
    qkv_gemm<float, float, 1><<<g1, 256, 0, stream>>>(
        flag, (const float*)d_in[0], (const float*)d_in[1],
        (const float*)d_in[2], (const float*)d_in[3], (float*)ybuf);
    attn_mix<float, float, 1><<<TOKENS / 4, 256, 0, stream>>>(
        flag, (const float*)ybuf, (float*)d_out);
  } else {
    qkv_gemm<float, ushort_t, 1><<<g1, 256, 0, stream>>>(
        flag, (const float*)d_in[0], (const float*)d_in[1],
        (const float*)d_in[2], (const float*)d_in[3], (ushort_t*)ybuf);
    attn_mix<ushort_t, float, 1><<<TOKENS / 4, 256, 0, stream>>>(
        flag, (const ushort_t*)ybuf, (float*)d_out);
  }
}

// Round 3
// 524.934 us; speedup vs baseline: 1.3633x; 1.3633x over previous
//
#include <hip/hip_runtime.h>
#include <stdint.h>
#include <stddef.h>

// EfficientAttention: B=4, L=4096, D=1024, H=16, hd=64. Inputs fp32 (proven R2).
// Pipeline (chunked, ws budget ~92 MB < known-good 96 MB):
//   split_w: W -> Wh/Wl bf16 (once)
//   per 8192-token chunk: split_x -> Xh/Xl bf16; gemm_split (pure bf16 MFMA,
//   3-term hi/lo); attn_mix (per-token head-mixing softmax matmuls) -> fp32 out.
#define TOKENS 16384
#define CHUNK  8192
#define DMODEL 1024

typedef short   short8 __attribute__((ext_vector_type(8)));
typedef __bf16  bfx8   __attribute__((ext_vector_type(8)));
typedef float   f32x4  __attribute__((ext_vector_type(4)));
typedef unsigned short ushort_t;
typedef unsigned short us4 __attribute__((ext_vector_type(4)));

__device__ inline float bf2f(ushort_t u) {
  union { unsigned int i; float f; } x; x.i = ((unsigned int)u) << 16; return x.f;
}
__device__ inline ushort_t f2bf(float f) {
  union { float f; unsigned int i; } x; x.f = f;
  unsigned int r = x.i + 0x7fff + ((x.i >> 16) & 1);
  return (ushort_t)(r >> 16);
}

// ---- MFMA wrapper: dual-signature hedge (short8 vs v8bf16 builtin arg) ----
template <typename V>
__device__ auto mfma16_(V a, V b, f32x4 c, int)
    -> decltype(__builtin_amdgcn_mfma_f32_16x16x32_bf16(a, b, c, 0, 0, 0)) {
  return __builtin_amdgcn_mfma_f32_16x16x32_bf16(a, b, c, 0, 0, 0);
}
template <typename V>
__device__ f32x4 mfma16_(V a, V b, f32x4 c, long) {
  return __builtin_amdgcn_mfma_f32_16x16x32_bf16(
      __builtin_bit_cast(bfx8, a), __builtin_bit_cast(bfx8, b), c, 0, 0, 0);
}
__device__ inline f32x4 MFMA16(short8 a, short8 b, f32x4 c) {
  return mfma16_(a, b, c, 0);
}

__device__ inline void gload_lds16(const void* g, void* l) {
  __builtin_amdgcn_global_load_lds(
      (const __attribute__((address_space(1))) unsigned int*)g,
      (__attribute__((address_space(3))) unsigned int*)l, 16, 0, 0);
}

// ---- fp32 -> bf16 hi + bf16 lo split (x ~= hi + lo), memory-bound pre-pass ----
__global__ __launch_bounds__(256) void split_f32(
    const float* __restrict__ src, ushort_t* __restrict__ hi,
    ushort_t* __restrict__ lo, int n4)
{
  int i = blockIdx.x * 256 + threadIdx.x;
  if (i >= n4) return;
  f32x4 x = ((const f32x4*)src)[i];
  us4 h, l;
  #pragma unroll
  for (int j = 0; j < 4; ++j) {
    ushort_t hh = f2bf(x[j]);
    h[j] = hh;
    l[j] = f2bf(x[j] - bf2f(hh));
  }
  ((us4*)hi)[i] = h;
  ((us4*)lo)[i] = l;
}

// ---------------- GEMM: Y[z] = Xc @ W[z]^T, pure-bf16 3-term split ----------------
// 128x128 tile, BK=32, 256 threads (4 waves, 2x2, 64x64/wave), m97 pattern.
__global__ __launch_bounds__(256, 2) void gemm_split(
    const ushort_t* __restrict__ Xh, const ushort_t* __restrict__ Xl,
    const ushort_t* __restrict__ Wh, const ushort_t* __restrict__ Wl,
    ushort_t* __restrict__ Y)
{
  __shared__ ushort_t Ah[128 * 32];  // 8 KB each, row-major stride 32
  __shared__ ushort_t Al[128 * 32];
  __shared__ ushort_t Bh[128 * 32];
  __shared__ ushort_t Bl[128 * 32];

  const int tid  = threadIdx.x;
  const int lane = tid & 63;
  const int wave = tid >> 6;
  const int quad = lane >> 4;
  const int l15  = lane & 15;
  const int wm   = wave & 1, wn = wave >> 1;

  const int m0 = blockIdx.x * 128;
  const int n0 = blockIdx.y * 128;
  const int z  = blockIdx.z;

  const ushort_t* Agh = Xh + (size_t)m0 * DMODEL;
  const ushort_t* Agl = Xl + (size_t)m0 * DMODEL;
  const ushort_t* Bgh = Wh + (size_t)z * DMODEL * DMODEL + (size_t)n0 * DMODEL;
  const ushort_t* Bgl = Wl + (size_t)z * DMODEL * DMODEL + (size_t)n0 * DMODEL;
  ushort_t* Yp = Y + (size_t)z * CHUNK * DMODEL;

  // staging: chunk c = p*256 + tid (16B = 8 bf16); row = c>>2, koff = (c&3)*8
  const int s_row = tid >> 2;
  const int s_off = (tid & 3) * 8;

  f32x4 acc[4][4] = {};

  const short8* Ahv = (const short8*)Ah;  // index = row*4 + k/8
  const short8* Alv = (const short8*)Al;
  const short8* Bhv = (const short8*)Bh;
  const short8* Blv = (const short8*)Bl;

  for (int k0 = 0; k0 < DMODEL; k0 += 32) {
    #pragma unroll
    for (int p = 0; p < 2; ++p) {
      size_t g = (size_t)(p * 64 + s_row) * DMODEL + k0 + s_off;
      int ldso = (p * 256 + wave * 64) * 16;
      gload_lds16(Agh + g, (char*)Ah + ldso);
      gload_lds16(Agl + g, (char*)Al + ldso);
      gload_lds16(Bgh + g, (char*)Bh + ldso);
      gload_lds16(Bgl + g, (char*)Bl + ldso);
    }
    __syncthreads();  // compiler drains vmcnt(0) before barrier

    short8 ah[4], al[4], bh[4], bl[4];
    #pragma unroll
    for (int i = 0; i < 4; ++i) {
      int idx = (wm * 64 + i * 16 + l15) * 4 + quad;  // A[m=lane&15][k=quad*8+j]
      ah[i] = Ahv[idx];
      al[i] = Alv[idx];
    }
    #pragma unroll
    for (int j = 0; j < 4; ++j) {
      int idx = (wn * 64 + j * 16 + l15) * 4 + quad;  // B[k][n] = W[n][k]
      bh[j] = Bhv[idx];
      bl[j] = Blv[idx];
    }

    #pragma unroll
    for (int i = 0; i < 4; ++i) {
      #pragma unroll
      for (int j = 0; j < 4; ++j) {
        acc[i][j] = MFMA16(ah[i], bh[j], acc[i][j]);
        acc[i][j] = MFMA16(al[i], bh[j], acc[i][j]);
        acc[i][j] = MFMA16(ah[i], bl[j], acc[i][j]);
      }
    }
    __syncthreads();
  }

  // C/D layout: col = lane&15, row = quad*4 + reg
  #pragma unroll
  for (int i = 0; i < 4; ++i) {
    #pragma unroll
    for (int j = 0; j < 4; ++j) {
      #pragma unroll
      for (int r = 0; r < 4; ++r) {
        int row = m0 + wm * 64 + i * 16 + quad * 4 + r;
        int col = n0 + wn * 64 + j * 16 + l15;
        Yp[(size_t)row * DMODEL + col] = f2bf(acc[i][j][r]);
      }
    }
  }
}

// ---------------- Phase 2: per-token mixing (1 wave/token) ----------------
__global__ __launch_bounds__(256) void attn_mix(
    const ushort_t* __restrict__ QKV, float* __restrict__ Out)
{
  __shared__ float sk_s[4][64 * 20];
  __shared__ float smq_s[4][16 * 64];

  const int tid  = threadIdx.x;
  const int lane = tid & 63;
  const int wv   = tid >> 6;
  const int tok  = blockIdx.x * 4 + wv;

  float* skl = sk_s[wv];
  float* smq = smq_s[wv];

  const size_t base = (size_t)tok * DMODEL;
  const ushort_t* Qg = QKV + base;
  const ushort_t* Kg = QKV + (size_t)CHUNK * DMODEL + base;
  const ushort_t* Vg = QKV + 2 * (size_t)CHUNK * DMODEL + base;

  float q[16], k[16], v[16];
  #pragma unroll
  for (int h = 0; h < 16; ++h) {
    q[h] = bf2f(Qg[h * 64 + lane]);
    k[h] = bf2f(Kg[h * 64 + lane]);
    v[h] = bf2f(Vg[h * 64 + lane]);
  }

  // sK[d][h] = softmax over h of K[h][d]; d = lane (per-lane)
  float mx = k[0];
  #pragma unroll
  for (int h = 1; h < 16; ++h) mx = fmaxf(mx, k[h]);
  float ssum = 0.f;
  #pragma unroll
  for (int h = 0; h < 16; ++h) { k[h] = __expf(k[h] - mx); ssum += k[h]; }
  float inv = 1.f / ssum;
  #pragma unroll
  for (int h = 0; h < 16; ++h) skl[lane * 20 + h] = k[h] * inv;

  // smQ[h][d] = softmax over d of Q[h][d]; wave reductions
  #pragma unroll
  for (int h = 0; h < 16; ++h) {
    float m = q[h];
    for (int off = 32; off; off >>= 1) m = fmaxf(m, __shfl_xor(m, off));
    float e = __expf(q[h] - m);
    float s2 = e;
    for (int off = 32; off; off >>= 1) s2 += __shfl_xor(s2, off);
    smq[h * 64 + lane] = e / s2;
  }

  __syncthreads();

  // tran_V col e(=lane): tv[d] = sum_h sK[d][h] * V[h][e]
  float tv[64];
  #pragma unroll
  for (int d = 0; d < 64; ++d) {
    const f32x4* r = (const f32x4*)(skl + d * 20);
    f32x4 s0 = r[0], s1 = r[1], s2 = r[2], s3 = r[3];
    float t = 0.f;
    #pragma unroll
    for (int h = 0; h < 4; ++h)
      t += s0[h] * v[h] + s1[h] * v[4 + h] + s2[h] * v[8 + h] + s3[h] * v[12 + h];
    tv[d] = t;
  }

  // out[h][e] = sum_d smQ[h][d] * tv[d]
  #pragma unroll
  for (int h = 0; h < 16; ++h) {
    const f32x4* r = (const f32x4*)(smq + h * 64);
    float o = 0.f;
    #pragma unroll
    for (int d4 = 0; d4 < 16; ++d4) {
      f32x4 w = r[d4];
      o += w[0] * tv[d4 * 4] + w[1] * tv[d4 * 4 + 1] + w[2] * tv[d4 * 4 + 2] + w[3] * tv[d4 * 4 + 3];
    }
    Out[base + h * 64 + lane] = o;
  }
}

extern "C" void kernel_launch(void* const* d_in, const int* in_sizes, int n_in,
                              void* d_out, int out_size, void* d_ws, size_t ws_size,
                              hipStream_t stream) {
  const float* X  = (const float*)d_in[0];
  const float* Wq = (const float*)d_in[1];
  const float* Wk = (const float*)d_in[2];
  const float* Wv = (const float*)d_in[3];
  float* Out = (float*)d_out;

  // ws layout (elems of ushort): Wh[3M] Wl[3M] Xh[8M] Xl[8M] Y[24M] = ~92 MB
  const size_t WSZ = (size_t)DMODEL * DMODEL;        // 1M elems per W
  const size_t XSZ = (size_t)CHUNK * DMODEL;         // 8M elems per chunk
  ushort_t* Wh = (ushort_t*)d_ws;
  ushort_t* Wl = Wh + 3 * WSZ;
  ushort_t* Xh = Wl + 3 * WSZ;
  ushort_t* Xl = Xh + XSZ;
  ushort_t* Y  = Xl + XSZ;                           // 3*XSZ elems

  // split weights (once per call)
  const int wn4 = (int)(WSZ / 4);
  const float* Ws[3] = {Wq, Wk, Wv};
  for (int z = 0; z < 3; ++z)
    split_f32<<<(wn4 + 255) / 256, 256, 0, stream>>>(
        Ws[z], Wh + (size_t)z * WSZ, Wl + (size_t)z * WSZ, wn4);

  const int xn4 = (int)(XSZ / 4);
  dim3 gg(CHUNK / 128, DMODEL / 128, 3);
  for (int c = 0; c < 2; ++c) {
    split_f32<<<(xn4 + 255) / 256, 256, 0, stream>>>(
        X + (size_t)c * XSZ, Xh, Xl, xn4);
    gemm_split<<<gg, 256, 0, stream>>>(Xh, Xl, Wh, Wl, Y);
    attn_mix<<<CHUNK / 4, 256, 0, stream>>>(Y, Out + (size_t)c * XSZ);
  }
}

// Round 4
// 432.546 us; speedup vs baseline: 1.6545x; 1.2136x over previous
//
#include <hip/hip_runtime.h>
#include <stdint.h>
#include <stddef.h>

// EfficientAttention: B=4, L=4096, D=1024, H=16, hd=64. Inputs fp32.
// X split to bf16 hi+lo (2-term MFMA: ah*bh + al*bh); W rounded to bf16 only
// (dropping the ah*bl term: adds ~0.008 absmax, budget 0.0295 — see R4 notes).
// Chunked over tokens to fit ws: Wh 6MB + Xh/Xl 32MB + Y 48MB = 86 MB.
#define TOKENS 16384
#define CHUNK  8192
#define DMODEL 1024

typedef short   short8 __attribute__((ext_vector_type(8)));
typedef __bf16  bfx8   __attribute__((ext_vector_type(8)));
typedef float   f32x4  __attribute__((ext_vector_type(4)));
typedef unsigned short ushort_t;
typedef unsigned short us4 __attribute__((ext_vector_type(4)));

__device__ inline float bf2f(ushort_t u) {
  union { unsigned int i; float f; } x; x.i = ((unsigned int)u) << 16; return x.f;
}
__device__ inline ushort_t f2bf(float f) {
  union { float f; unsigned int i; } x; x.f = f;
  unsigned int r = x.i + 0x7fff + ((x.i >> 16) & 1);
  return (ushort_t)(r >> 16);
}

// ---- MFMA wrapper: dual-signature hedge (short8 vs v8bf16 builtin arg) ----
template <typename V>
__device__ auto mfma16_(V a, V b, f32x4 c, int)
    -> decltype(__builtin_amdgcn_mfma_f32_16x16x32_bf16(a, b, c, 0, 0, 0)) {
  return __builtin_amdgcn_mfma_f32_16x16x32_bf16(a, b, c, 0, 0, 0);
}
template <typename V>
__device__ f32x4 mfma16_(V a, V b, f32x4 c, long) {
  return __builtin_amdgcn_mfma_f32_16x16x32_bf16(
      __builtin_bit_cast(bfx8, a), __builtin_bit_cast(bfx8, b), c, 0, 0, 0);
}
__device__ inline f32x4 MFMA16(short8 a, short8 b, f32x4 c) {
  return mfma16_(a, b, c, 0);
}

__device__ inline void gload_lds16(const void* g, void* l) {
  __builtin_amdgcn_global_load_lds(
      (const __attribute__((address_space(1))) unsigned int*)g,
      (__attribute__((address_space(3))) unsigned int*)l, 16, 0, 0);
}

// ---- W -> bf16 (hi only), all three weights in one launch ----
__global__ __launch_bounds__(256) void conv_w(
    const float* __restrict__ Wq, const float* __restrict__ Wk,
    const float* __restrict__ Wv, ushort_t* __restrict__ Wh, int n4)
{
  int i = blockIdx.x * 256 + threadIdx.x;
  if (i >= n4) return;
  const float* src = (blockIdx.y == 0) ? Wq : ((blockIdx.y == 1) ? Wk : Wv);
  f32x4 x = ((const f32x4*)src)[i];
  us4 h;
  #pragma unroll
  for (int j = 0; j < 4; ++j) h[j] = f2bf(x[j]);
  ((us4*)(Wh + (size_t)blockIdx.y * DMODEL * DMODEL))[i] = h;
}

// ---- X -> bf16 hi + lo ----
__global__ __launch_bounds__(256) void split_x(
    const float* __restrict__ src, ushort_t* __restrict__ hi,
    ushort_t* __restrict__ lo, int n4)
{
  int i = blockIdx.x * 256 + threadIdx.x;
  if (i >= n4) return;
  f32x4 x = ((const f32x4*)src)[i];
  us4 h, l;
  #pragma unroll
  for (int j = 0; j < 4; ++j) {
    ushort_t hh = f2bf(x[j]);
    h[j] = hh;
    l[j] = f2bf(x[j] - bf2f(hh));
  }
  ((us4*)hi)[i] = h;
  ((us4*)lo)[i] = l;
}

// ---------------- GEMM: Y[z] = Xc @ W[z]^T, 2-term split ----------------
// 128x128 tile, BK=32, 256 threads (4 waves, 2x2, 64x64/wave), m97 pattern.
// LDS 24 KB -> 4 blocks/CU at __launch_bounds__(256,4). VGPR ~68 (R3).
__global__ __launch_bounds__(256, 4) void gemm2(
    const ushort_t* __restrict__ Xh, const ushort_t* __restrict__ Xl,
    const ushort_t* __restrict__ Wh, ushort_t* __restrict__ Y)
{
  __shared__ ushort_t Ah[128 * 32];  // 8 KB each, row-major stride 32
  __shared__ ushort_t Al[128 * 32];
  __shared__ ushort_t Bh[128 * 32];

  const int tid  = threadIdx.x;
  const int lane = tid & 63;
  const int wave = tid >> 6;
  const int quad = lane >> 4;
  const int l15  = lane & 15;
  const int wm   = wave & 1, wn = wave >> 1;

  const int m0 = blockIdx.x * 128;
  const int n0 = blockIdx.y * 128;
  const int z  = blockIdx.z;

  const ushort_t* Agh = Xh + (size_t)m0 * DMODEL;
  const ushort_t* Agl = Xl + (size_t)m0 * DMODEL;
  const ushort_t* Bgh = Wh + (size_t)z * DMODEL * DMODEL + (size_t)n0 * DMODEL;
  ushort_t* Yp = Y + (size_t)z * CHUNK * DMODEL;

  // staging: chunk c = p*256 + tid (16B = 8 bf16); row = c>>2, koff = (c&3)*8
  const int s_row = tid >> 2;
  const int s_off = (tid & 3) * 8;

  f32x4 acc[4][4] = {};

  const short8* Ahv = (const short8*)Ah;  // index = row*4 + k/8
  const short8* Alv = (const short8*)Al;
  const short8* Bhv = (const short8*)Bh;

  for (int k0 = 0; k0 < DMODEL; k0 += 32) {
    #pragma unroll
    for (int p = 0; p < 2; ++p) {
      size_t g = (size_t)(p * 64 + s_row) * DMODEL + k0 + s_off;
      int ldso = (p * 256 + wave * 64) * 16;
      gload_lds16(Agh + g, (char*)Ah + ldso);
      gload_lds16(Agl + g, (char*)Al + ldso);
      gload_lds16(Bgh + g, (char*)Bh + ldso);
    }
    __syncthreads();  // compiler drains vmcnt(0) before barrier

    short8 ah[4], al[4], bh[4];
    #pragma unroll
    for (int i = 0; i < 4; ++i) {
      int idx = (wm * 64 + i * 16 + l15) * 4 + quad;  // A[m=lane&15][k=quad*8+j]
      ah[i] = Ahv[idx];
      al[i] = Alv[idx];
    }
    #pragma unroll
    for (int j = 0; j < 4; ++j)
      bh[j] = Bhv[(wn * 64 + j * 16 + l15) * 4 + quad]; // B[k][n] = W[n][k]

    #pragma unroll
    for (int i = 0; i < 4; ++i) {
      #pragma unroll
      for (int j = 0; j < 4; ++j) {
        acc[i][j] = MFMA16(ah[i], bh[j], acc[i][j]);
        acc[i][j] = MFMA16(al[i], bh[j], acc[i][j]);
      }
    }
    __syncthreads();
  }

  // C/D layout: col = lane&15, row = quad*4 + reg
  #pragma unroll
  for (int i = 0; i < 4; ++i) {
    #pragma unroll
    for (int j = 0; j < 4; ++j) {
      #pragma unroll
      for (int r = 0; r < 4; ++r) {
        int row = m0 + wm * 64 + i * 16 + quad * 4 + r;
        int col = n0 + wn * 64 + j * 16 + l15;
        Yp[(size_t)row * DMODEL + col] = f2bf(acc[i][j][r]);
      }
    }
  }
}

// ---------------- Phase 2: per-token mixing (1 wave/token) ----------------
__global__ __launch_bounds__(256) void attn_mix(
    const ushort_t* __restrict__ QKV, float* __restrict__ Out)
{
  __shared__ float sk_s[4][64 * 20];
  __shared__ float smq_s[4][16 * 64];

  const int tid  = threadIdx.x;
  const int lane = tid & 63;
  const int wv   = tid >> 6;
  const int tok  = blockIdx.x * 4 + wv;

  float* skl = sk_s[wv];
  float* smq = smq_s[wv];

  const size_t base = (size_t)tok * DMODEL;
  const ushort_t* Qg = QKV + base;
  const ushort_t* Kg = QKV + (size_t)CHUNK * DMODEL + base;
  const ushort_t* Vg = QKV + 2 * (size_t)CHUNK * DMODEL + base;

  float q[16], k[16], v[16];
  #pragma unroll
  for (int h = 0; h < 16; ++h) {
    q[h] = bf2f(Qg[h * 64 + lane]);
    k[h] = bf2f(Kg[h * 64 + lane]);
    v[h] = bf2f(Vg[h * 64 + lane]);
  }

  // sK[d][h] = softmax over h of K[h][d]; d = lane (per-lane)
  float mx = k[0];
  #pragma unroll
  for (int h = 1; h < 16; ++h) mx = fmaxf(mx, k[h]);
  float ssum = 0.f;
  #pragma unroll
  for (int h = 0; h < 16; ++h) { k[h] = __expf(k[h] - mx); ssum += k[h]; }
  float inv = 1.f / ssum;
  #pragma unroll
  for (int h = 0; h < 16; ++h) skl[lane * 20 + h] = k[h] * inv;

  // smQ[h][d] = softmax over d of Q[h][d]; wave reductions
  #pragma unroll
  for (int h = 0; h < 16; ++h) {
    float m = q[h];
    for (int off = 32; off; off >>= 1) m = fmaxf(m, __shfl_xor(m, off));
    float e = __expf(q[h] - m);
    float s2 = e;
    for (int off = 32; off; off >>= 1) s2 += __shfl_xor(s2, off);
    smq[h * 64 + lane] = e / s2;
  }

  __syncthreads();

  // tran_V col e(=lane): tv[d] = sum_h sK[d][h] * V[h][e]
  float tv[64];
  #pragma unroll
  for (int d = 0; d < 64; ++d) {
    const f32x4* r = (const f32x4*)(skl + d * 20);
    f32x4 s0 = r[0], s1 = r[1], s2 = r[2], s3 = r[3];
    float t = 0.f;
    #pragma unroll
    for (int h = 0; h < 4; ++h)
      t += s0[h] * v[h] + s1[h] * v[4 + h] + s2[h] * v[8 + h] + s3[h] * v[12 + h];
    tv[d] = t;
  }

  // out[h][e] = sum_d smQ[h][d] * tv[d]
  #pragma unroll
  for (int h = 0; h < 16; ++h) {
    const f32x4* r = (const f32x4*)(smq + h * 64);
    float o = 0.f;
    #pragma unroll
    for (int d4 = 0; d4 < 16; ++d4) {
      f32x4 w = r[d4];
      o += w[0] * tv[d4 * 4] + w[1] * tv[d4 * 4 + 1] + w[2] * tv[d4 * 4 + 2] + w[3] * tv[d4 * 4 + 3];
    }
    Out[base + h * 64 + lane] = o;
  }
}

extern "C" void kernel_launch(void* const* d_in, const int* in_sizes, int n_in,
                              void* d_out, int out_size, void* d_ws, size_t ws_size,
                              hipStream_t stream) {
  const float* X  = (const float*)d_in[0];
  const float* Wq = (const float*)d_in[1];
  const float* Wk = (const float*)d_in[2];
  const float* Wv = (const float*)d_in[3];
  float* Out = (float*)d_out;

  // ws layout (ushort elems): Wh[3M] Xh[8M] Xl[8M] Y[24M] = 86 MB
  const size_t WSZ = (size_t)DMODEL * DMODEL;
  const size_t XSZ = (size_t)CHUNK * DMODEL;
  ushort_t* Wh = (ushort_t*)d_ws;
  ushort_t* Xh = Wh + 3 * WSZ;
  ushort_t* Xl = Xh + XSZ;
  ushort_t* Y  = Xl + XSZ;

  const int wn4 = (int)(WSZ / 4);
  dim3 gw((wn4 + 255) / 256, 3);
  conv_w<<<gw, 256, 0, stream>>>(Wq, Wk, Wv, Wh, wn4);

  const int xn4 = (int)(XSZ / 4);
  dim3 gg(CHUNK / 128, DMODEL / 128, 3);
  for (int c = 0; c < 2; ++c) {
    split_x<<<(xn4 + 255) / 256, 256, 0, stream>>>(X + (size_t)c * XSZ, Xh, Xl, xn4);
    gemm2<<<gg, 256, 0, stream>>>(Xh, Xl, Wh, Y);
    attn_mix<<<CHUNK / 4, 256, 0, stream>>>(Y, Out + (size_t)c * XSZ);
  }
}